// Round 1
// baseline (155.208 us; speedup 1.0000x reference)
//
#include <hip/hip_runtime.h>

typedef __attribute__((ext_vector_type(4))) float  float4v;
typedef __attribute__((ext_vector_type(4))) short  short4v;
typedef __attribute__((ext_vector_type(8))) short  short8v;
typedef __attribute__((ext_vector_type(4))) float  f32x4;

// f32 -> bf16 round-to-nearest-even (3 VALU ops, no header dependency)
__device__ __forceinline__ short f2bf(float f) {
  unsigned int u = __float_as_uint(f);
  u = u + 0x7fffu + ((u >> 16) & 1u);
  return (short)(u >> 16);
}

// XOR swizzle: row-major [row][ld] bf16 tile, byte ^= ((row&7)<<4)  => short idx k ^= ((row&7)<<3)
__device__ __forceinline__ int swz(int row, int k, int ld) {
  return row * ld + (k ^ ((row & 7) << 3));
}

// -------------------------------------------------------------------------
// Kernel 1: ht[b][f][m] = bf16( sum_d feat[b][m][d] * W[d][f] )   (H^T, bf16)
// grid (N/128, B), 256 threads. 128x128 tile per block, K=D=128.
// -------------------------------------------------------------------------
__global__ __launch_bounds__(256) void k1_feat_x_w(
    const float* __restrict__ feat, const float* __restrict__ W,
    short* __restrict__ ht, int N) {
  __shared__ short Fs[128 * 128];  // feat tile [m][d] bf16, swizzled
  __shared__ short Ws[128 * 128];  // W^T      [f][d] bf16, swizzled
  const int t = threadIdx.x;
  const int batch = blockIdx.y;
  const int m0 = blockIdx.x * 128;
  const float* fb = feat + (size_t)batch * N * 128;

  // stage Fs: 8 passes of 16 rows, 2x float4 -> 1x b128 per thread
  {
    const int row = t >> 4;        // 0..15
    const int d = (t & 15) * 8;
#pragma unroll
    for (int i = 0; i < 8; ++i) {
      const int r = i * 16 + row;
      const float4v* src = (const float4v*)(fb + (size_t)(m0 + r) * 128 + d);
      float4v v0 = src[0], v1 = src[1];
      short8v s;
      s[0]=f2bf(v0[0]); s[1]=f2bf(v0[1]); s[2]=f2bf(v0[2]); s[3]=f2bf(v0[3]);
      s[4]=f2bf(v1[0]); s[5]=f2bf(v1[1]); s[6]=f2bf(v1[2]); s[7]=f2bf(v1[3]);
      *(short8v*)(&Fs[swz(r, d, 128)]) = s;
    }
  }
  // stage Ws (transpose of W): scalar strided reads (W is 64KB, L2-hot)
  {
    const int f = t >> 1;
    const int dbase = (t & 1) * 64;
#pragma unroll
    for (int g = 0; g < 16; ++g) {
      const int d = dbase + g * 4;
      short4v s;
#pragma unroll
      for (int i = 0; i < 4; ++i) s[i] = f2bf(W[(size_t)(d + i) * 128 + f]);
      *(short4v*)(&Ws[swz(f, d, 128)]) = s;
    }
  }
  __syncthreads();

  const int lane = t & 63;
  const int wid = t >> 6;
  const int wm = (wid >> 1) * 64;   // wave m offset (2x2 waves, 64x64 each)
  const int wn = (wid & 1) * 64;    // wave f offset
  const int lr = lane & 15;
  const int lk = (lane >> 4) * 8;

  f32x4 acc[4][4];
#pragma unroll
  for (int i = 0; i < 4; ++i)
#pragma unroll
    for (int j = 0; j < 4; ++j) acc[i][j] = (f32x4){0.f, 0.f, 0.f, 0.f};

#pragma unroll
  for (int kk = 0; kk < 4; ++kk) {
    const int k = kk * 32 + lk;
    short8v a[4], b[4];
#pragma unroll
    for (int mi = 0; mi < 4; ++mi)
      a[mi] = *(const short8v*)(&Fs[swz(wm + mi * 16 + lr, k, 128)]);
#pragma unroll
    for (int ni = 0; ni < 4; ++ni)
      b[ni] = *(const short8v*)(&Ws[swz(wn + ni * 16 + lr, k, 128)]);
#pragma unroll
    for (int mi = 0; mi < 4; ++mi)
#pragma unroll
      for (int ni = 0; ni < 4; ++ni)
        acc[mi][ni] = __builtin_amdgcn_mfma_f32_16x16x32_bf16(a[mi], b[ni], acc[mi][ni], 0, 0, 0);
  }

  // write ht[b][f][m]; D-frag: col(f)=lane&15, row(m)=(lane>>4)*4+r
  short* hb = ht + (size_t)batch * 128 * N;
#pragma unroll
  for (int mi = 0; mi < 4; ++mi) {
    const int m = m0 + wm + mi * 16 + (lane >> 4) * 4;
#pragma unroll
    for (int ni = 0; ni < 4; ++ni) {
      const int f = wn + ni * 16 + lr;
      short4v s;
#pragma unroll
      for (int r = 0; r < 4; ++r) s[r] = f2bf(acc[mi][ni][r]);
      *(short4v*)(hb + (size_t)f * N + m) = s;
    }
  }
}

// -------------------------------------------------------------------------
// Kernel 2: out[b][m][f] = relu( sum_k A[b][m][k] * H[k][f] + bias[f] )
// grid (N/64, B), 256 threads. 64x128 tile, BK=64, K=N=4096.
// A staged f32->bf16 in-register; H read from ht (bf16, k-contiguous).
// -------------------------------------------------------------------------
__global__ __launch_bounds__(256) void k2_a_x_h(
    const float* __restrict__ A, const short* __restrict__ ht,
    const float* __restrict__ bias, float* __restrict__ out, int N) {
  __shared__ short As[64 * 64];    // A tile [m][k] bf16, swizzled (8 KB)
  __shared__ short Hs[128 * 64];   // H^T tile [f][k] bf16, swizzled (16 KB)
  const int t = threadIdx.x;
  const int batch = blockIdx.y;
  const int m0 = blockIdx.x * 64;
  const float* Ab = A + (size_t)batch * N * N;
  const short* hb = ht + (size_t)batch * 128 * N;

  const int lane = t & 63;
  const int wid = t >> 6;
  const int wm = (wid >> 1) * 32;  // wave m offset (2x2 waves, 32x64 each)
  const int wn = (wid & 1) * 64;   // wave f offset
  const int lr = lane & 15;
  const int lk = (lane >> 4) * 8;

  const int srow = t >> 3;         // 0..31 (staging row)
  const int skc = (t & 7) * 8;     // staging k offset (8 elems)

  f32x4 acc[2][4];
#pragma unroll
  for (int i = 0; i < 2; ++i)
#pragma unroll
    for (int j = 0; j < 4; ++j) acc[i][j] = (f32x4){0.f, 0.f, 0.f, 0.f};

  for (int k0 = 0; k0 < N; k0 += 64) {
    // stage As: 2 passes x 32 rows; 2x float4 -> cvt -> 1x b128
#pragma unroll
    for (int i = 0; i < 2; ++i) {
      const int r = i * 32 + srow;
      const float4v* src = (const float4v*)(Ab + (size_t)(m0 + r) * N + k0 + skc);
      float4v v0 = src[0], v1 = src[1];
      short8v s;
      s[0]=f2bf(v0[0]); s[1]=f2bf(v0[1]); s[2]=f2bf(v0[2]); s[3]=f2bf(v0[3]);
      s[4]=f2bf(v1[0]); s[5]=f2bf(v1[1]); s[6]=f2bf(v1[2]); s[7]=f2bf(v1[3]);
      *(short8v*)(&As[swz(r, skc, 64)]) = s;
    }
    // stage Hs: 4 passes x 32 rows; 16B bf16 copy
#pragma unroll
    for (int i = 0; i < 4; ++i) {
      const int f = i * 32 + srow;
      short8v v = *(const short8v*)(hb + (size_t)f * N + k0 + skc);
      *(short8v*)(&Hs[swz(f, skc, 64)]) = v;
    }
    __syncthreads();

#pragma unroll
    for (int kk = 0; kk < 2; ++kk) {
      const int k = kk * 32 + lk;
      short8v a[2], b[4];
#pragma unroll
      for (int mi = 0; mi < 2; ++mi)
        a[mi] = *(const short8v*)(&As[swz(wm + mi * 16 + lr, k, 64)]);
#pragma unroll
      for (int ni = 0; ni < 4; ++ni)
        b[ni] = *(const short8v*)(&Hs[swz(wn + ni * 16 + lr, k, 64)]);
#pragma unroll
      for (int mi = 0; mi < 2; ++mi)
#pragma unroll
        for (int ni = 0; ni < 4; ++ni)
          acc[mi][ni] = __builtin_amdgcn_mfma_f32_16x16x32_bf16(a[mi], b[ni], acc[mi][ni], 0, 0, 0);
    }
    __syncthreads();
  }

  // epilogue: bias + relu, f32 store
  float* ob = out + (size_t)batch * N * 128;
#pragma unroll
  for (int ni = 0; ni < 4; ++ni) {
    const int f = wn + ni * 16 + lr;
    const float bv = bias[f];
#pragma unroll
    for (int mi = 0; mi < 2; ++mi) {
      const int mbase = m0 + wm + mi * 16 + (lane >> 4) * 4;
#pragma unroll
      for (int r = 0; r < 4; ++r) {
        const float v = acc[mi][ni][r] + bv;
        ob[(size_t)(mbase + r) * 128 + f] = fmaxf(v, 0.f);
      }
    }
  }
}

extern "C" void kernel_launch(void* const* d_in, const int* in_sizes, int n_in,
                              void* d_out, int out_size, void* d_ws, size_t ws_size,
                              hipStream_t stream) {
  const float* feat = (const float*)d_in[0];  // [B,N,128]
  const float* A    = (const float*)d_in[1];  // [B,N,N]
  const float* W    = (const float*)d_in[2];  // [128,128]
  const float* bias = (const float*)d_in[3];  // [128]
  float* out = (float*)d_out;                 // [B,N,128]

  const int featN = in_sizes[0];      // B*N*128
  const int aN    = in_sizes[1];      // B*N*N
  const int BN    = featN / 128;      // B*N
  const int N     = aN / BN;
  const int Bb    = BN / N;

  short* ht = (short*)d_ws;           // [B][128][N] bf16 = B*128*N*2 bytes

  dim3 g1(N / 128, Bb), g2(N / 64, Bb), blk(256);
  hipLaunchKernelGGL(k1_feat_x_w, g1, blk, 0, stream, feat, W, ht, N);
  hipLaunchKernelGGL(k2_a_x_h, g2, blk, 0, stream, A, ht, bias, out, N);
}

// Round 2
// 85.721 us; speedup vs baseline: 1.8106x; 1.8106x over previous
//
#include <hip/hip_runtime.h>

typedef __attribute__((ext_vector_type(4))) float  float4v;
typedef __attribute__((ext_vector_type(4))) short  short4v;
typedef __attribute__((ext_vector_type(8))) short  short8v;
typedef __attribute__((ext_vector_type(4))) float  f32x4;

// f32 -> bf16 round-to-nearest-even
__device__ __forceinline__ short f2bf(float f) {
  unsigned int u = __float_as_uint(f);
  u = u + 0x7fffu + ((u >> 16) & 1u);
  return (short)(u >> 16);
}

// XOR swizzle: row-major [row][ld] bf16 tile, byte ^= ((row&7)<<4) => short k ^= ((row&7)<<3)
__device__ __forceinline__ int swz(int row, int k, int ld) {
  return row * ld + (k ^ ((row & 7) << 3));
}

// async global->LDS, 16B per lane; LDS dest = wave-uniform base + lane*16
__device__ __forceinline__ void gll16(const void* g, void* l) {
  __builtin_amdgcn_global_load_lds(
      (const __attribute__((address_space(1))) unsigned int*)g,
      (__attribute__((address_space(3))) unsigned int*)l, 16, 0, 0);
}

__device__ __forceinline__ short8v cvt8(float4v v0, float4v v1) {
  short8v s;
  s[0]=f2bf(v0[0]); s[1]=f2bf(v0[1]); s[2]=f2bf(v0[2]); s[3]=f2bf(v0[3]);
  s[4]=f2bf(v1[0]); s[5]=f2bf(v1[1]); s[6]=f2bf(v1[2]); s[7]=f2bf(v1[3]);
  return s;
}

// -------------------------------------------------------------------------
// Kernel 1: ht[b][f][m] = bf16( sum_d feat[b][m][d] * W[d][f] )   (H^T, bf16)
// grid (N/64, B), 256 threads. 64x128 tile, K=D=128 (single K-step).
// -------------------------------------------------------------------------
__global__ __launch_bounds__(256) void k1_feat_x_w(
    const float* __restrict__ feat, const float* __restrict__ W,
    short* __restrict__ ht, int N) {
  __shared__ short Fs[64 * 128];   // feat tile [m][d] bf16, swizzled
  __shared__ short Ws[128 * 128];  // W^T      [f][d] bf16, swizzled
  const int t = threadIdx.x;
  const int batch = blockIdx.y;
  const int m0 = blockIdx.x * 64;
  const float* fb = feat + (size_t)batch * N * 128;

  {
    const int row = t >> 4;        // 0..15
    const int d = (t & 15) * 8;
#pragma unroll
    for (int i = 0; i < 4; ++i) {
      const int r = i * 16 + row;
      const float4v* src = (const float4v*)(fb + (size_t)(m0 + r) * 128 + d);
      *(short8v*)(&Fs[swz(r, d, 128)]) = cvt8(src[0], src[1]);
    }
  }
  {  // Ws = W^T: [f][d]
    const int f = t >> 1;
    const int dbase = (t & 1) * 64;
#pragma unroll
    for (int g = 0; g < 16; ++g) {
      const int d = dbase + g * 4;
      short4v s;
#pragma unroll
      for (int i = 0; i < 4; ++i) s[i] = f2bf(W[(size_t)(d + i) * 128 + f]);
      *(short4v*)(&Ws[swz(f, d, 128)]) = s;
    }
  }
  __syncthreads();

  const int lane = t & 63, wid = t >> 6;
  const int wm = (wid >> 1) * 32, wn = (wid & 1) * 64;
  const int lr = lane & 15, lk = (lane >> 4) * 8;

  f32x4 acc[2][4];
#pragma unroll
  for (int i = 0; i < 2; ++i)
#pragma unroll
    for (int j = 0; j < 4; ++j) acc[i][j] = (f32x4){0.f, 0.f, 0.f, 0.f};

#pragma unroll
  for (int kk = 0; kk < 4; ++kk) {
    const int k = kk * 32 + lk;
    short8v a[2], b[4];
#pragma unroll
    for (int mi = 0; mi < 2; ++mi)
      a[mi] = *(const short8v*)(&Fs[swz(wm + mi * 16 + lr, k, 128)]);
#pragma unroll
    for (int ni = 0; ni < 4; ++ni)
      b[ni] = *(const short8v*)(&Ws[swz(wn + ni * 16 + lr, k, 128)]);
#pragma unroll
    for (int mi = 0; mi < 2; ++mi)
#pragma unroll
      for (int ni = 0; ni < 4; ++ni)
        acc[mi][ni] = __builtin_amdgcn_mfma_f32_16x16x32_bf16(a[mi], b[ni], acc[mi][ni], 0, 0, 0);
  }

  // ht[b][f][m]; D-frag: col(f)=lane&15, row(m)=(lane>>4)*4+r
  short* hb = ht + (size_t)batch * 128 * N;
#pragma unroll
  for (int mi = 0; mi < 2; ++mi) {
    const int m = m0 + wm + mi * 16 + (lane >> 4) * 4;
#pragma unroll
    for (int ni = 0; ni < 4; ++ni) {
      const int f = wn + ni * 16 + lr;
      short4v s;
#pragma unroll
      for (int r = 0; r < 4; ++r) s[r] = f2bf(acc[mi][ni][r]);
      *(short4v*)(hb + (size_t)f * N + m) = s;
    }
  }
}

// -------------------------------------------------------------------------
// Kernel 2: out[b][m][f] = relu( sum_k A[b][m][k] * H[k][f] + bias[f] )
// grid (N/32, B) = 512 blocks (2/CU), 256 threads. 32x128 tile, BK=64.
// Double-buffered LDS; A reg-staged (f32->bf16 cvt); H via global_load_lds
// with pre-swizzled global source; one barrier per K-step.
// -------------------------------------------------------------------------
__global__ __launch_bounds__(256) void k2_a_x_h(
    const float* __restrict__ A, const short* __restrict__ ht,
    const float* __restrict__ bias, float* __restrict__ out, int N) {
  __shared__ short As[2][32 * 64];    // 2 x 4 KB
  __shared__ short Hs[2][128 * 64];   // 2 x 16 KB
  const int t = threadIdx.x;
  const int batch = blockIdx.y;
  const int m0 = blockIdx.x * 32;
  const float* Ab = A + (size_t)batch * N * N;
  const short* hb = ht + (size_t)batch * 128 * N;

  const int lane = t & 63, wid = t >> 6;
  const int wm = (wid >> 1) * 16, wn = (wid & 1) * 64;
  const int lr = lane & 15, lk = (lane >> 4) * 8;

  // A staging map: thread covers 8 consecutive f32 (32B, 2x dwordx4)
  const int arow = t >> 3;        // 0..31
  const int akc = (t & 7) * 8;

  // H staging map (per wave, 4 gll16 calls of 16B/lane):
  const int hf = lane >> 3;          // row-within-8 (== f&7)
  const int hks = (lane & 7) * 8;    // k slot (shorts)

  float4v va0, va1;

  auto loadA = [&](int k0) {
    const float* p = Ab + (size_t)(m0 + arow) * N + k0 + akc;
    va0 = ((const float4v*)p)[0];
    va1 = ((const float4v*)p)[1];
  };
  auto writeA = [&](int buf) {
    *(short8v*)(&As[buf][swz(arow, akc, 64)]) = cvt8(va0, va1);
  };
  auto stageH = [&](int k0, int buf) {
#pragma unroll
    for (int i = 0; i < 4; ++i) {
      const int fb8 = (wid * 4 + i) * 8;         // wave-uniform f base
      const int f = fb8 + hf;
      // pre-swizzled global source so the LINEAR lds write lands swizzled
      const short* g = hb + (size_t)f * N + k0 + (hks ^ (hf << 3));
      gll16(g, &Hs[buf][fb8 * 64]);
    }
  };

  f32x4 acc[4];
#pragma unroll
  for (int j = 0; j < 4; ++j) acc[j] = (f32x4){0.f, 0.f, 0.f, 0.f};

  // prologue: stage tile 0 into buf 0
  loadA(0);
  stageH(0, 0);
  writeA(0);            // compiler inserts vmcnt wait for va0/va1
  __syncthreads();      // drains gll writes too

  const int NT = N / 64;
  for (int tt = 0; tt < NT; ++tt) {
    const int cur = tt & 1;
    const bool pf = (tt + 1 < NT);
    if (pf) {
      loadA((tt + 1) * 64);           // HBM loads in flight over MFMA phase
      stageH((tt + 1) * 64, cur ^ 1); // L2 loads direct to LDS
    }
#pragma unroll
    for (int kk = 0; kk < 2; ++kk) {
      const int k = kk * 32 + lk;
      short8v a = *(const short8v*)(&As[cur][swz(wm + lr, k, 64)]);
      short8v b[4];
#pragma unroll
      for (int ni = 0; ni < 4; ++ni)
        b[ni] = *(const short8v*)(&Hs[cur][swz(wn + ni * 16 + lr, k, 64)]);
#pragma unroll
      for (int ni = 0; ni < 4; ++ni)
        acc[ni] = __builtin_amdgcn_mfma_f32_16x16x32_bf16(a, b[ni], acc[ni], 0, 0, 0);
    }
    if (pf) writeA(cur ^ 1);
    __syncthreads();    // vmcnt(0)+barrier: next tile fully staged
  }

  // epilogue: bias + relu
  float* ob = out + (size_t)batch * N * 128;
#pragma unroll
  for (int ni = 0; ni < 4; ++ni) {
    const int f = wn + ni * 16 + lr;
    const float bv = bias[f];
    const int mbase = m0 + wm + (lane >> 4) * 4;
#pragma unroll
    for (int r = 0; r < 4; ++r)
      ob[(size_t)(mbase + r) * 128 + f] = fmaxf(acc[ni][r] + bv, 0.f);
  }
}

extern "C" void kernel_launch(void* const* d_in, const int* in_sizes, int n_in,
                              void* d_out, int out_size, void* d_ws, size_t ws_size,
                              hipStream_t stream) {
  const float* feat = (const float*)d_in[0];  // [B,N,128]
  const float* A    = (const float*)d_in[1];  // [B,N,N]
  const float* W    = (const float*)d_in[2];  // [128,128]
  const float* bias = (const float*)d_in[3];  // [128]
  float* out = (float*)d_out;                 // [B,N,128]

  const int featN = in_sizes[0];      // B*N*128
  const int aN    = in_sizes[1];      // B*N*N
  const int BN    = featN / 128;      // B*N
  const int N     = aN / BN;
  const int Bb    = BN / N;

  short* ht = (short*)d_ws;           // [B][128][N] bf16

  dim3 g1(N / 64, Bb), g2(N / 32, Bb), blk(256);
  hipLaunchKernelGGL(k1_feat_x_w, g1, blk, 0, stream, feat, W, ht, N);
  hipLaunchKernelGGL(k2_a_x_h, g2, blk, 0, stream, A, ht, bias, out, N);
}